// Round 7
// baseline (341.401 us; speedup 1.0000x reference)
//
#include <hip/hip_runtime.h>
#include <math.h>

#define QD 256
#define QN 1024
#define TT 8192

typedef __bf16 bf16x8 __attribute__((ext_vector_type(8)));
typedef float  f32x16 __attribute__((ext_vector_type(16)));
typedef unsigned short ushort_t;
typedef unsigned short us8 __attribute__((ext_vector_type(8)));

// LDS map (k_mega), total 53248 -> 3 blocks/CU needs total regs/wave <= ~80 (see launch bounds)
#define PL  0        // A planes [3][16kc][64cl][16B] = 49152 ; after GEMM1: t-h [0,16K), t32 [16K,48K)
#define MU_ 49152    // muS[8][32] f32 = 1024 (wave-pre-reduced)
#define LM_ 50176    // lnMu[32] f32
#define T2_ 50304    // tn2A[32] f32 (atomicAdd)
#define TR_ 50432    // thrR[32] u32 (atomicMax, order-encoded)
#define CN_ 50560    // cnt[32] i32
#define CC_ 50688    // candC[32][40] u16 = 2560
#define SMEM_TOTAL 53248
#define CCAP 40

// exact 3-way bf16 split (truncation; x = h+m+l up to ~2^-21|x|)
__device__ __forceinline__ void split3(float x, ushort_t& h, ushort_t& m, ushort_t& l) {
    unsigned int xu = __float_as_uint(x);
    h = (ushort_t)(xu >> 16);
    float hf = __uint_as_float(xu & 0xFFFF0000u);
    float r1 = x - hf;                       // exact
    unsigned int r1u = __float_as_uint(r1);
    m = (ushort_t)(r1u >> 16);
    float mf = __uint_as_float(r1u & 0xFFFF0000u);
    float r2 = r1 - mf;                      // exact
    l = (ushort_t)(__float_as_uint(r2) >> 16);
}
__device__ __forceinline__ f32x16 MF(bf16x8 a, bf16x8 b, f32x16 c) {
    return __builtin_amdgcn_mfma_f32_32x32x16_bf16(a, b, c, 0, 0, 0);
}
// order-preserving float<->uint encode (for atomicMax on float values); init 0 < all encodings
__device__ __forceinline__ unsigned fenc(float f) {
    unsigned u = __float_as_uint(f);
    return (u & 0x80000000u) ? ~u : (u | 0x80000000u);
}
__device__ __forceinline__ float fdec(unsigned u) {
    return (u & 0x80000000u) ? __uint_as_float(u ^ 0x80000000u) : __uint_as_float(~u);
}

// ---------- k_pre: codebook normalize (h-plane + fp32) AND [M=convw^T@proj] planes, wsum, p1 ----
// bx<256: 4 codes/block. bx in [256,320): 4 M-cols/block. bx==320: wsum; bx==321: p1.
__global__ __launch_bounds__(256) void k_pre(const float* __restrict__ convw,
                                             const float* __restrict__ proj,
                                             const float* __restrict__ cb,
                                             ushort_t* __restrict__ cbph,
                                             float* __restrict__ cbn,
                                             ushort_t* __restrict__ w2p,
                                             float* __restrict__ wsum,
                                             float* __restrict__ p1) {
    int bx = blockIdx.x, t = threadIdx.x;
    if (bx < 256) {
        int c = bx*4 + (t>>6), lane = t&63;
        float4 v = ((const float4*)(cb + (size_t)c*QD))[lane];
        float ss = v.x*v.x + v.y*v.y + v.z*v.z + v.w*v.w;
        #pragma unroll
        for (int off = 32; off > 0; off >>= 1) ss += __shfl_down(ss, off);
        ss = __shfl(ss, 0);
        float inv = 1.0f/fmaxf(sqrtf(ss), 1e-12f);
        float4 vn = make_float4(v.x*inv, v.y*inv, v.z*inv, v.w*inv);
        *(float4*)(cbn + (size_t)c*QD + 4*lane) = vn;
        float vals[4] = {vn.x, vn.y, vn.z, vn.w};
        #pragma unroll
        for (int i = 0; i < 4; ++i) {
            int k = 4*lane + i;
            size_t base = ((size_t)(k>>4)*32 + (c>>5))*512 + (((k>>3)&1)*32 + (c&31))*8 + (k&7);
            cbph[base] = (ushort_t)(__float_as_uint(vals[i]) >> 16);
        }
    } else if (bx < 320) {
        int col0 = (bx - 256) * 4;
        __shared__ float4 colv4[512];
        const float* src = proj + col0;
        colv4[t]       = *(const float4*)(src + (size_t)t * 256);
        colv4[t + 256] = *(const float4*)(src + (size_t)(t + 256) * 256);
        __syncthreads();
        float a0 = 0.f, a1 = 0.f, a2 = 0.f, a3 = 0.f;
        #pragma unroll 16
        for (int d = 0; d < 512; ++d) {
            float wv = convw[d*256 + t];
            float4 cv = colv4[d];
            a0 += wv*cv.x; a1 += wv*cv.y; a2 += wv*cv.z; a3 += wv*cv.w;
        }
        float accs[4] = {a0, a1, a2, a3};
        #pragma unroll
        for (int j = 0; j < 4; ++j) {
            int col = col0 + j;
            ushort_t hb, mb, lb; split3(accs[j], hb, mb, lb);
            size_t base = ((size_t)(t>>4)*8 + (col>>5))*512 + (((t>>3)&1)*32 + (col&31))*8 + (t&7);
            w2p[base] = hb;
            w2p[base + 65536] = mb;
            w2p[base + 131072] = lb;
        }
    } else if (bx == 320) {
        float s = 0.f;
        #pragma unroll 32
        for (int d = 0; d < 512; ++d) s += convw[d*256 + t];
        wsum[t] = s;
    } else {
        float s = 0.f;
        #pragma unroll 32
        for (int d = 0; d < 512; ++d) s += proj[d*256 + t];
        p1[t] = s;
    }
}

// ---------- k_mega: 32 tokens/block. patch->split3 -> GEMM1(M, 6 prod, single 16-AGPR acc,
//            B ping-pong) -> t=V-mu*p1 -> GEMM2 hh-screen (2 sweeps x 2 tiles, 32-AGPR) ->
//            group-parallel exact fp32 refine -> argmax.
//            launch_bounds(512,6): hard 6 waves/EU floor -> unified reg budget ~80/wave ->
//            3 blocks/CU (LDS 53248*3 = 159744 <= 163840). ----
__global__ __launch_bounds__(512, 6) void k_mega(const float* __restrict__ fbank,
                                                 const ushort_t* __restrict__ w2p,
                                                 const ushort_t* __restrict__ cbph,
                                                 const float* __restrict__ cbn,
                                                 const float* __restrict__ wsum,
                                                 const float* __restrict__ p1,
                                                 int* __restrict__ out) {
    __shared__ char smem[SMEM_TOTAL];
    float*    muS   = (float*)(smem + MU_);
    float*    lnMuS = (float*)(smem + LM_);
    float*    tn2A  = (float*)(smem + T2_);
    unsigned* thrR  = (unsigned*)(smem + TR_);
    int*      cntS  = (int*)(smem + CN_);
    ushort_t* candS = (ushort_t*)(smem + CC_);

    int tid = threadIdx.x;
    int n0 = blockIdx.x * 32;
    int w = tid >> 6, lane = tid & 63;
    int n31 = lane & 31, h = lane >> 5;
    size_t loff = (size_t)lane * 16;
    const char* w2pc = (const char*)w2p;
    const char* cbhc = (const char*)cbph;

    auto loadB1 = [&](int kcv, bf16x8 (&dst)[3]) {
        #pragma unroll
        for (int q = 0; q < 3; ++q)
            dst[q] = *(const bf16x8*)(w2pc + (size_t)q*131072 + (size_t)(kcv*8 + w)*1024 + loff);
    };
    // sweep sw covers code tiles 16sw + {w, w+8}
    auto loadB2s = [&](int sw, int kcv, bf16x8 (&dst)[2]) {
        dst[0] = *(const bf16x8*)(cbhc + (size_t)(kcv*32 + 16*sw + w    )*1024 + loff);
        dst[1] = *(const bf16x8*)(cbhc + (size_t)(kcv*32 + 16*sw + w + 8)*1024 + loff);
    };
    auto loadA = [&](int kcv, bf16x8 (&a)[3]) {
        #pragma unroll
        for (int p = 0; p < 3; ++p)
            a[p] = *(const bf16x8*)(smem + p*16384 + kcv*1024 + loff);
    };
    auto compute6 = [&](bf16x8 (&a)[3], bf16x8 (&b)[3], f32x16& acc) {
        acc = MF(a[0], b[0], acc);
        acc = MF(a[0], b[1], acc);
        acc = MF(a[1], b[0], acc);
        acc = MF(a[1], b[1], acc);
        acc = MF(a[0], b[2], acc);
        acc = MF(a[2], b[0], acc);
    };

    // ---- prefetch fbank (4 float4/thread; L3/L2-warm across iterations) ----
    float4 va[2], vb[2];
    #pragma unroll
    for (int i = 0; i < 2; ++i) {
        int id = tid + 512*i;
        int kc = id >> 6, cl = id & 63;
        int tok = cl & 31, hh2 = cl >> 5;
        int n = n0 + tok;
        int b = n >> 12, r = n & 4095, th = r >> 3, wm = r & 7;
        const float* src = fbank + ((size_t)(b*TT + th*16 + kc))*128 + wm*16 + hh2*8;
        va[i] = ((const float4*)src)[0];
        vb[i] = ((const float4*)src)[1];
    }
    int wb0 = 16*(tid >> 6) + 8*((tid >> 5) & 1);

    if (tid < 32) { tn2A[tid] = 0.f; thrR[tid] = 0u; cntS[tid] = 0; }

    // ---- stage patch -> 3 bf16 planes; mu partial (exact fp32 vals) folded in.
    //      wsum slices loaded in-loop (L2-hot) to keep staging register pressure low. ----
    float mupart = 0.f;
    #pragma unroll
    for (int i = 0; i < 2; ++i) {
        int id = tid + 512*i;
        int kc = id >> 6, cl = id & 63;
        float4 wA = *(const float4*)(wsum + wb0 + i*128);
        float4 wB = *(const float4*)(wsum + wb0 + i*128 + 4);
        float vals[8] = {va[i].x, va[i].y, va[i].z, va[i].w, vb[i].x, vb[i].y, vb[i].z, vb[i].w};
        float wv[8]   = {wA.x, wA.y, wA.z, wA.w, wB.x, wB.y, wB.z, wB.w};
        us8 hv, mv, lv;
        #pragma unroll
        for (int j = 0; j < 8; ++j) {
            ushort_t a_, b_, c_; split3(vals[j], a_, b_, c_);
            hv[j] = a_; mv[j] = b_; lv[j] = c_;
            mupart += vals[j] * wv[j];
        }
        char* cp = smem + kc*1024 + cl*16;
        *(us8*)cp = hv;
        *(us8*)(cp + 16384) = mv;
        *(us8*)(cp + 32768) = lv;
    }

    // first GEMM1 B-tile: in flight under muS store + barrier drain
    bf16x8 bA[3], bB[3];
    loadB1(0, bA);

    // wave pre-reduce mu partials (token = tid&31 appears in lanes l and l+32)
    float mu2 = mupart + __shfl_xor(mupart, 32);
    if (lane < 32) muS[w*32 + lane] = mu2;
    __syncthreads();                                   // B2: planes + muS + inits ready

    if (tid < 32) {
        float pm = 0.f;
        #pragma unroll
        for (int s = 0; s < 8; ++s) pm += muS[s*32 + tid];
        lnMuS[tid] = pm * (1.f/512.f);                 // published at B3
    }

    // ========== GEMM1: V[32][256] = patch @ M, split-3 (6 prod), single acc (16 AGPR) ======
    f32x16 acc;
    #pragma unroll
    for (int r2 = 0; r2 < 16; ++r2) acc[r2] = 0.f;
    for (int kc = 0; kc < 16; kc += 2) {
        loadB1(kc + 1, bB);
        { bf16x8 a[3]; loadA(kc, a); compute6(a, bA, acc); }
        if (kc + 2 < 16) loadB1(kc + 2, bA);
        { bf16x8 a[3]; loadA(kc + 1, a); compute6(a, bB, acc); }
    }

    float p1v = p1[32*w + n31];                        // L2-hot scalar, drains at B3
    bf16x8 qA[2], qB[2];
    loadB2s(0, 0, qA);                                 // flies across epilogue (drains at B3)

    __syncthreads();                                   // B3: GEMM1 LDS reads done; lnMu ready

    // ---- t = V - mu*p1 (rs is argmax-neutral); write t32 (f32) + t-h (bf16 trunc); ||t||^2 ----
    {
        int q = 32*w + n31;
        #pragma unroll
        for (int reg = 0; reg < 16; ++reg) {
            int tok = (reg&3) + 8*(reg>>2) + 4*h;
            float tv = acc[reg] - lnMuS[tok]*p1v;
            *(float*)(smem + 16384 + tok*1024 + q*4) = tv;
            *(ushort_t*)(smem + (q>>4)*1024 + (((q>>3)&1)*32 + tok)*16 + (q&7)*2)
                = (ushort_t)(__float_as_uint(tv) >> 16);
            float sq2 = tv*tv;
            #pragma unroll
            for (int msk = 1; msk < 32; msk <<= 1) sq2 += __shfl_xor(sq2, msk);
            if (n31 == 0) atomicAdd(&tn2A[tok], sq2);
        }
    }
    __syncthreads();                                   // B4: t-h / t32 / tn2A ready

    // ========== GEMM2 screen: sim_hh = t_h @ cb_h^T, 2 sweeps x 2 tiles (32-AGPR acc) ======
    #pragma unroll
    for (int sw = 0; sw < 2; ++sw) {
        f32x16 s0, s1;
        #pragma unroll
        for (int r2 = 0; r2 < 16; ++r2) { s0[r2] = 0.f; s1[r2] = 0.f; }
        for (int kc = 0; kc < 16; kc += 2) {
            loadB2s(sw, kc + 1, qB);
            {
                bf16x8 ah = *(const bf16x8*)(smem + kc*1024 + loff);
                s0 = MF(ah, qA[0], s0); s1 = MF(ah, qA[1], s1);
            }
            if (kc + 2 < 16) loadB2s(sw, kc + 2, qA);
            else if (sw == 0) loadB2s(1, 0, qA);       // preload next sweep across barrier
            {
                bf16x8 ah = *(const bf16x8*)(smem + (kc+1)*1024 + loff);
                s0 = MF(ah, qB[0], s0); s1 = MF(ah, qB[1], s1);
            }
        }
        // wave-local per-token max -> thrR via atomicMax (order-encoded)
        #pragma unroll
        for (int reg = 0; reg < 16; ++reg) {
            int tok = (reg&3) + 8*(reg>>2) + 4*h;
            float m = fmaxf(s0[reg], s1[reg]);
            #pragma unroll
            for (int msk = 1; msk < 32; msk <<= 1) m = fmaxf(m, __shfl_xor(m, msk));
            if (n31 == 0) atomicMax(&thrR[tok], fenc(m));
        }
        __syncthreads();                               // B5/B6: this sweep's maxes visible
        // append candidates; thr inline. Any later-sweep contamination only RAISES thr and
        // stays >= globalmax - window; window 0.04 > 2e = 0.032 keeps true argmax in set.
        #pragma unroll
        for (int reg = 0; reg < 16; ++reg) {
            int tok = (reg&3) + 8*(reg>>2) + 4*h;
            float th_ = fdec(thrR[tok]) - 0.04f*sqrtf(tn2A[tok]);
            if (s0[reg] >= th_) { int p = atomicAdd(&cntS[tok], 1); if (p < CCAP) candS[tok*CCAP + p] = (ushort_t)(512*sw + 32*w + n31); }
            if (s1[reg] >= th_) { int p = atomicAdd(&cntS[tok], 1); if (p < CCAP) candS[tok*CCAP + p] = (ushort_t)(512*sw + 32*(w + 8) + n31); }
        }
    }
    __syncthreads();                                   // B7: candidates final

    // ---- exact fp32 refine: 16 candidates in parallel (4-lane groups); wave w owns 4 tokens.
    //      lane sub handles float4 indices {4j+sub} -> banks {0,4,8,12}+16j : conflict-free ----
    int grp = lane >> 2, sub = lane & 3;
    #pragma unroll 1
    for (int tk = 0; tk < 4; ++tk) {
        int tok = 4*w + tk;
        int cnt = cntS[tok];
        bool full = (cnt > CCAP);                      // provable fallback: scan everything
        int nc = full ? 1024 : cnt;
        const float4* tp4 = (const float4*)(smem + 16384 + (size_t)tok*1024);
        float bv = -3.4e38f; int bi = 0x7fffffff;
        #pragma unroll 1
        for (int base = 0; base < nc; base += 16) {
            int ci = base + grp;
            int code = 0x7fffffff;
            float part = 0.f;
            if (ci < nc) {
                code = full ? ci : (int)candS[tok*CCAP + ci];
                const float4* cp4 = (const float4*)(cbn + (size_t)code*256);
                float a0 = 0.f, a1 = 0.f, a2 = 0.f, a3 = 0.f;
                #pragma unroll
                for (int jj = 0; jj < 16; jj += 4) {
                    float4 c0 = cp4[(jj  )*4 + sub], t0 = tp4[(jj  )*4 + sub];
                    float4 c1 = cp4[(jj+1)*4 + sub], t1 = tp4[(jj+1)*4 + sub];
                    float4 c2 = cp4[(jj+2)*4 + sub], t2 = tp4[(jj+2)*4 + sub];
                    float4 c3 = cp4[(jj+3)*4 + sub], t3 = tp4[(jj+3)*4 + sub];
                    a0 += c0.x*t0.x + c0.y*t0.y + c0.z*t0.z + c0.w*t0.w;
                    a1 += c1.x*t1.x + c1.y*t1.y + c1.z*t1.z + c1.w*t1.w;
                    a2 += c2.x*t2.x + c2.y*t2.y + c2.z*t2.z + c2.w*t2.w;
                    a3 += c3.x*t3.x + c3.y*t3.y + c3.z*t3.z + c3.w*t3.w;
                }
                part = (a0 + a1) + (a2 + a3);
            }
            // full dot within the 4-lane group (ci uniform across the group)
            float d = part;
            d += __shfl_xor(d, 1);
            d += __shfl_xor(d, 2);
            if (ci >= nc) d = -3.4e38f;
            // cross-group argmax, lowest-index tie-break
            #pragma unroll
            for (int msk = 4; msk < 64; msk <<= 1) {
                float od = __shfl_xor(d, msk);
                int   oc = __shfl_xor(code, msk);
                if (od > d || (od == d && oc < code)) { d = od; code = oc; }
            }
            if (d > bv || (d == bv && code < bi)) { bv = d; bi = code; }
        }
        if (lane == 0) out[n0 + tok] = bi;
    }
}

extern "C" void kernel_launch(void* const* d_in, const int* in_sizes, int n_in,
                              void* d_out, int out_size, void* d_ws, size_t ws_size,
                              hipStream_t stream) {
    const float* fbank = (const float*)d_in[0];   // 16 x 8192 x 128
    const float* convw = (const float*)d_in[1];   // [512][256]
    const float* proj  = (const float*)d_in[2];   // [512][256]
    const float* cbook = (const float*)d_in[3];   // [1024][256]
    int* out = (int*)d_out;                       // 65536 int32

    char* ws = (char*)d_ws;
    ushort_t* cbph = (ushort_t*)ws;                  // 512 KB codebook h-plane
    float* cbn     = (float*)(ws + 0x080000);        // 1 MB normalized codebook fp32
    ushort_t* w2p  = (ushort_t*)(ws + 0x180000);     // 384 KB M planes (split-3)
    float* wsum    = (float*)(ws + 0x1E0000);        // 1 KB
    float* p1      = (float*)(ws + 0x1E1000);        // 1 KB

    hipLaunchKernelGGL(k_pre,  dim3(322),  dim3(256), 0, stream,
                       convw, proj, cbook, cbph, cbn, w2p, wsum, p1);
    hipLaunchKernelGGL(k_mega, dim3(2048), dim3(512), 0, stream,
                       fbank, w2p, cbph, cbn, wsum, p1, out);
}

// Round 8
// 298.831 us; speedup vs baseline: 1.1425x; 1.1425x over previous
//
#include <hip/hip_runtime.h>
#include <math.h>

#define QD 256
#define QN 1024
#define TT 8192

typedef __bf16 bf16x8 __attribute__((ext_vector_type(8)));
typedef float  f32x16 __attribute__((ext_vector_type(16)));
typedef unsigned short ushort_t;
typedef unsigned short us8 __attribute__((ext_vector_type(8)));
typedef unsigned short us4 __attribute__((ext_vector_type(4)));

// LDS map (k_mega), total 53760 -> 2 blocks/CU (r6 pareto point: no spills, 64+32 regs)
#define PL  0        // A planes [3][16kc][64cl][16B] = 49152 ; after GEMM1: t-h [0,16K), t32 [16K,48K)
#define MU_ 49152    // muS[8][32] f32 = 1024 (wave-pre-reduced)
#define LM_ 50176    // lnMu[32] f32
#define T2_ 50304    // tn2A[32] f32 (atomicAdd)
#define TR_ 50432    // thrR[32] u32 (atomicMax, order-encoded)
#define CN_ 50560    // cnt[32] i32
#define CC_ 50688    // candC[32][48] u16 = 3072
#define SMEM_TOTAL 53760
#define CCAP 48

// exact 3-way bf16 split (truncation; x = h+m+l up to ~2^-21|x|)
__device__ __forceinline__ void split3(float x, ushort_t& h, ushort_t& m, ushort_t& l) {
    unsigned int xu = __float_as_uint(x);
    h = (ushort_t)(xu >> 16);
    float hf = __uint_as_float(xu & 0xFFFF0000u);
    float r1 = x - hf;                       // exact
    unsigned int r1u = __float_as_uint(r1);
    m = (ushort_t)(r1u >> 16);
    float mf = __uint_as_float(r1u & 0xFFFF0000u);
    float r2 = r1 - mf;                      // exact
    l = (ushort_t)(__float_as_uint(r2) >> 16);
}
__device__ __forceinline__ f32x16 MF(bf16x8 a, bf16x8 b, f32x16 c) {
    return __builtin_amdgcn_mfma_f32_32x32x16_bf16(a, b, c, 0, 0, 0);
}
// order-preserving float<->uint encode (for atomicMax on float values); init 0 < all encodings
__device__ __forceinline__ unsigned fenc(float f) {
    unsigned u = __float_as_uint(f);
    return (u & 0x80000000u) ? ~u : (u | 0x80000000u);
}
__device__ __forceinline__ float fdec(unsigned u) {
    return (u & 0x80000000u) ? __uint_as_float(u ^ 0x80000000u) : __uint_as_float(~u);
}

// ---------- k_pre v2: parallelism + coalescing; numerics bit-identical to prior rounds ----------
// grid 257 x 512 threads:
//   bx < 128  : codebook, 8 codes/block (1 per wave; SAME 64-lane reduce order); us4 cbph store
//   bx in [128,256) : M = convw^T @ proj, 2 cols/block, 1 thread = 1 (row,col) chain d=0..511
//   bx == 256 : wsum (t<256) and p1 (t>=256), same chains as before
__global__ __launch_bounds__(512) void k_pre(const float* __restrict__ convw,
                                             const float* __restrict__ proj,
                                             const float* __restrict__ cb,
                                             ushort_t* __restrict__ cbph,
                                             float* __restrict__ cbn,
                                             ushort_t* __restrict__ w2p,
                                             float* __restrict__ wsum,
                                             float* __restrict__ p1) {
    int bx = blockIdx.x, t = threadIdx.x;
    if (bx < 128) {
        int w = t >> 6, lane = t & 63;
        int c = bx*8 + w;
        float4 v = ((const float4*)(cb + (size_t)c*QD))[lane];
        float ss = v.x*v.x + v.y*v.y + v.z*v.z + v.w*v.w;
        #pragma unroll
        for (int off = 32; off > 0; off >>= 1) ss += __shfl_down(ss, off);
        ss = __shfl(ss, 0);
        float inv = 1.0f/fmaxf(sqrtf(ss), 1e-12f);
        float4 vn = make_float4(v.x*inv, v.y*inv, v.z*inv, v.w*inv);
        *(float4*)(cbn + (size_t)c*QD + 4*lane) = vn;
        // k = 4*lane + i (i<4) are 4 consecutive u16 at one swizzled base -> single 8B store
        int k0 = 4*lane;
        size_t base = ((size_t)(k0>>4)*32 + (c>>5))*512 + (((k0>>3)&1)*32 + (c&31))*8 + (k0&7);
        us4 hv4;
        hv4[0] = (ushort_t)(__float_as_uint(vn.x) >> 16);
        hv4[1] = (ushort_t)(__float_as_uint(vn.y) >> 16);
        hv4[2] = (ushort_t)(__float_as_uint(vn.z) >> 16);
        hv4[3] = (ushort_t)(__float_as_uint(vn.w) >> 16);
        *(us4*)(cbph + base) = hv4;
    } else if (bx < 256) {
        int col0 = (bx - 128)*2;
        int tt = t & 255, cs = t >> 8;
        int col = col0 + cs;
        __shared__ float colv[2][512];
        colv[cs][tt]       = proj[(size_t)tt*256 + col];
        colv[cs][tt + 256] = proj[(size_t)(tt+256)*256 + col];
        __syncthreads();
        float acc = 0.f;
        #pragma unroll 32
        for (int d = 0; d < 512; ++d) acc += convw[d*256 + tt] * colv[cs][d];
        ushort_t hb, mb, lb; split3(acc, hb, mb, lb);
        size_t base = ((size_t)(tt>>4)*8 + (col>>5))*512 + (((tt>>3)&1)*32 + (col&31))*8 + (tt&7);
        w2p[base] = hb;
        w2p[base + 65536] = mb;
        w2p[base + 131072] = lb;
    } else {
        if (t < 256) {
            float s = 0.f;
            #pragma unroll 32
            for (int d = 0; d < 512; ++d) s += convw[d*256 + t];
            wsum[t] = s;
        } else {
            int u = t - 256;
            float s = 0.f;
            #pragma unroll 32
            for (int d = 0; d < 512; ++d) s += proj[d*256 + u];
            p1[u] = s;
        }
    }
}

// ---------- k_mega: r6 verbatim (measured 227 us, 64 arch + 32 AGPR, zero spill) ----------
__global__ __launch_bounds__(512, 4) void k_mega(const float* __restrict__ fbank,
                                                 const ushort_t* __restrict__ w2p,
                                                 const ushort_t* __restrict__ cbph,
                                                 const float* __restrict__ cbn,
                                                 const float* __restrict__ wsum,
                                                 const float* __restrict__ p1,
                                                 int* __restrict__ out) {
    __shared__ char smem[SMEM_TOTAL];
    float*    muS   = (float*)(smem + MU_);
    float*    lnMuS = (float*)(smem + LM_);
    float*    tn2A  = (float*)(smem + T2_);
    unsigned* thrR  = (unsigned*)(smem + TR_);
    int*      cntS  = (int*)(smem + CN_);
    ushort_t* candS = (ushort_t*)(smem + CC_);

    int tid = threadIdx.x;
    int n0 = blockIdx.x * 32;
    int w = tid >> 6, lane = tid & 63;
    int n31 = lane & 31, h = lane >> 5;
    size_t loff = (size_t)lane * 16;
    const char* w2pc = (const char*)w2p;
    const char* cbhc = (const char*)cbph;

    auto loadB1 = [&](int kcv, bf16x8 (&dst)[3]) {
        #pragma unroll
        for (int q = 0; q < 3; ++q)
            dst[q] = *(const bf16x8*)(w2pc + (size_t)q*131072 + (size_t)(kcv*8 + w)*1024 + loff);
    };
    // sweep sw covers code tiles 16sw + {w, w+8}
    auto loadB2s = [&](int sw, int kcv, bf16x8 (&dst)[2]) {
        dst[0] = *(const bf16x8*)(cbhc + (size_t)(kcv*32 + 16*sw + w    )*1024 + loff);
        dst[1] = *(const bf16x8*)(cbhc + (size_t)(kcv*32 + 16*sw + w + 8)*1024 + loff);
    };
    auto loadA = [&](int kcv, bf16x8 (&a)[3]) {
        #pragma unroll
        for (int p = 0; p < 3; ++p)
            a[p] = *(const bf16x8*)(smem + p*16384 + kcv*1024 + loff);
    };
    auto compute6 = [&](bf16x8 (&a)[3], bf16x8 (&b)[3], f32x16& acc) {
        acc = MF(a[0], b[0], acc);
        acc = MF(a[0], b[1], acc);
        acc = MF(a[1], b[0], acc);
        acc = MF(a[1], b[1], acc);
        acc = MF(a[0], b[2], acc);
        acc = MF(a[2], b[0], acc);
    };

    // ---- prefetch fbank (4 float4/thread) + wsum slices (all L2-hot after first blocks) ----
    float4 va[2], vb[2];
    #pragma unroll
    for (int i = 0; i < 2; ++i) {
        int id = tid + 512*i;
        int kc = id >> 6, cl = id & 63;
        int tok = cl & 31, hh2 = cl >> 5;
        int n = n0 + tok;
        int b = n >> 12, r = n & 4095, th = r >> 3, wm = r & 7;
        const float* src = fbank + ((size_t)(b*TT + th*16 + kc))*128 + wm*16 + hh2*8;
        va[i] = ((const float4*)src)[0];
        vb[i] = ((const float4*)src)[1];
    }
    int wb0 = 16*(tid >> 6) + 8*((tid >> 5) & 1);
    float4 w00 = *(const float4*)(wsum + wb0);
    float4 w01 = *(const float4*)(wsum + wb0 + 4);
    float4 w10 = *(const float4*)(wsum + wb0 + 128);
    float4 w11 = *(const float4*)(wsum + wb0 + 132);

    if (tid < 32) { tn2A[tid] = 0.f; thrR[tid] = 0u; cntS[tid] = 0; }

    float wsv[2][8];
    wsv[0][0]=w00.x; wsv[0][1]=w00.y; wsv[0][2]=w00.z; wsv[0][3]=w00.w;
    wsv[0][4]=w01.x; wsv[0][5]=w01.y; wsv[0][6]=w01.z; wsv[0][7]=w01.w;
    wsv[1][0]=w10.x; wsv[1][1]=w10.y; wsv[1][2]=w10.z; wsv[1][3]=w10.w;
    wsv[1][4]=w11.x; wsv[1][5]=w11.y; wsv[1][6]=w11.z; wsv[1][7]=w11.w;

    // ---- stage patch -> 3 bf16 planes; mu partial (exact fp32 vals) folded in ----
    float mupart = 0.f;
    #pragma unroll
    for (int i = 0; i < 2; ++i) {
        int id = tid + 512*i;
        int kc = id >> 6, cl = id & 63;
        float vals[8] = {va[i].x, va[i].y, va[i].z, va[i].w, vb[i].x, vb[i].y, vb[i].z, vb[i].w};
        us8 hv, mv, lv;
        #pragma unroll
        for (int j = 0; j < 8; ++j) {
            ushort_t a_, b_, c_; split3(vals[j], a_, b_, c_);
            hv[j] = a_; mv[j] = b_; lv[j] = c_;
            mupart += vals[j] * wsv[i][j];
        }
        char* cp = smem + kc*1024 + cl*16;
        *(us8*)cp = hv;
        *(us8*)(cp + 16384) = mv;
        *(us8*)(cp + 32768) = lv;
    }

    // first GEMM1 B-tile: in flight under muS store + barrier drain
    bf16x8 bA[3], bB[3];
    loadB1(0, bA);

    // wave pre-reduce mu partials (token = tid&31 appears in lanes l and l+32)
    float mu2 = mupart + __shfl_xor(mupart, 32);
    if (lane < 32) muS[w*32 + lane] = mu2;
    __syncthreads();                                   // B2: planes + muS + inits ready

    if (tid < 32) {
        float pm = 0.f;
        #pragma unroll
        for (int s = 0; s < 8; ++s) pm += muS[s*32 + tid];
        lnMuS[tid] = pm * (1.f/512.f);                 // published at B3
    }

    // ========== GEMM1: V[32][256] = patch @ M, split-3 (6 prod), B ping-pong ==========
    f32x16 accE, accO;
    #pragma unroll
    for (int r2 = 0; r2 < 16; ++r2) { accE[r2] = 0.f; accO[r2] = 0.f; }
    for (int kc = 0; kc < 16; kc += 2) {
        loadB1(kc + 1, bB);
        { bf16x8 a[3]; loadA(kc, a); compute6(a, bA, accE); }
        if (kc + 2 < 16) loadB1(kc + 2, bA);
        { bf16x8 a[3]; loadA(kc + 1, a); compute6(a, bB, accO); }
    }

    float p1v = p1[32*w + n31];                        // L2-hot scalar, drains at B3
    bf16x8 qA[2], qB[2];
    loadB2s(0, 0, qA);                                 // flies across epilogue (drains at B3)

    __syncthreads();                                   // B3: GEMM1 LDS reads done; lnMu ready

    // ---- t = V - mu*p1 (rs is argmax-neutral); write t32 (f32) + t-h (bf16 trunc); ||t||^2 ----
    {
        int q = 32*w + n31;
        #pragma unroll
        for (int reg = 0; reg < 16; ++reg) {
            int tok = (reg&3) + 8*(reg>>2) + 4*h;
            float tv = (accE[reg] + accO[reg]) - lnMuS[tok]*p1v;
            *(float*)(smem + 16384 + tok*1024 + q*4) = tv;
            *(ushort_t*)(smem + (q>>4)*1024 + (((q>>3)&1)*32 + tok)*16 + (q&7)*2)
                = (ushort_t)(__float_as_uint(tv) >> 16);
            float sq2 = tv*tv;
            #pragma unroll
            for (int msk = 1; msk < 32; msk <<= 1) sq2 += __shfl_xor(sq2, msk);
            if (n31 == 0) atomicAdd(&tn2A[tok], sq2);
        }
    }
    __syncthreads();                                   // B4: t-h / t32 / tn2A ready

    // ========== GEMM2 screen: sim_hh = t_h @ cb_h^T, 2 sweeps x 2 tiles (32-AGPR acc) ======
    #pragma unroll
    for (int sw = 0; sw < 2; ++sw) {
        f32x16 s0, s1;
        #pragma unroll
        for (int r2 = 0; r2 < 16; ++r2) { s0[r2] = 0.f; s1[r2] = 0.f; }
        for (int kc = 0; kc < 16; kc += 2) {
            loadB2s(sw, kc + 1, qB);
            {
                bf16x8 ah = *(const bf16x8*)(smem + kc*1024 + loff);
                s0 = MF(ah, qA[0], s0); s1 = MF(ah, qA[1], s1);
            }
            if (kc + 2 < 16) loadB2s(sw, kc + 2, qA);
            else if (sw == 0) loadB2s(1, 0, qA);       // preload next sweep across barrier
            {
                bf16x8 ah = *(const bf16x8*)(smem + (kc+1)*1024 + loff);
                s0 = MF(ah, qB[0], s0); s1 = MF(ah, qB[1], s1);
            }
        }
        // wave-local per-token max -> thrR via atomicMax (order-encoded)
        #pragma unroll
        for (int reg = 0; reg < 16; ++reg) {
            int tok = (reg&3) + 8*(reg>>2) + 4*h;
            float m = fmaxf(s0[reg], s1[reg]);
            #pragma unroll
            for (int msk = 1; msk < 32; msk <<= 1) m = fmaxf(m, __shfl_xor(m, msk));
            if (n31 == 0) atomicMax(&thrR[tok], fenc(m));
        }
        __syncthreads();                               // B5/B6: this sweep's maxes visible
        // append candidates; thr inline. Any later-sweep contamination only RAISES thr and
        // stays >= globalmax - window; window 0.04 > 2e = 0.032 keeps true argmax in set.
        #pragma unroll
        for (int reg = 0; reg < 16; ++reg) {
            int tok = (reg&3) + 8*(reg>>2) + 4*h;
            float th_ = fdec(thrR[tok]) - 0.04f*sqrtf(tn2A[tok]);
            if (s0[reg] >= th_) { int p = atomicAdd(&cntS[tok], 1); if (p < CCAP) candS[tok*CCAP + p] = (ushort_t)(512*sw + 32*w + n31); }
            if (s1[reg] >= th_) { int p = atomicAdd(&cntS[tok], 1); if (p < CCAP) candS[tok*CCAP + p] = (ushort_t)(512*sw + 32*(w + 8) + n31); }
        }
    }
    __syncthreads();                                   // B7: candidates final

    // ---- exact fp32 refine: 16 candidates in parallel (4-lane groups); wave w owns 4 tokens.
    //      lane sub handles float4 indices {4j+sub} -> banks {0,4,8,12}+16j : conflict-free ----
    int grp = lane >> 2, sub = lane & 3;
    #pragma unroll 1
    for (int tk = 0; tk < 4; ++tk) {
        int tok = 4*w + tk;
        int cnt = cntS[tok];
        bool full = (cnt > CCAP);                      // provable fallback: scan everything
        int nc = full ? 1024 : cnt;
        const float4* tp4 = (const float4*)(smem + 16384 + (size_t)tok*1024);
        float bv = -3.4e38f; int bi = 0x7fffffff;
        #pragma unroll 1
        for (int base = 0; base < nc; base += 16) {
            int ci = base + grp;
            int code = 0x7fffffff;
            float part = 0.f;
            if (ci < nc) {
                code = full ? ci : (int)candS[tok*CCAP + ci];
                const float4* cp4 = (const float4*)(cbn + (size_t)code*256);
                float a0 = 0.f, a1 = 0.f, a2 = 0.f, a3 = 0.f;
                #pragma unroll
                for (int jj = 0; jj < 16; jj += 4) {
                    float4 c0 = cp4[(jj  )*4 + sub], t0 = tp4[(jj  )*4 + sub];
                    float4 c1 = cp4[(jj+1)*4 + sub], t1 = tp4[(jj+1)*4 + sub];
                    float4 c2 = cp4[(jj+2)*4 + sub], t2 = tp4[(jj+2)*4 + sub];
                    float4 c3 = cp4[(jj+3)*4 + sub], t3 = tp4[(jj+3)*4 + sub];
                    a0 += c0.x*t0.x + c0.y*t0.y + c0.z*t0.z + c0.w*t0.w;
                    a1 += c1.x*t1.x + c1.y*t1.y + c1.z*t1.z + c1.w*t1.w;
                    a2 += c2.x*t2.x + c2.y*t2.y + c2.z*t2.z + c2.w*t2.w;
                    a3 += c3.x*t3.x + c3.y*t3.y + c3.z*t3.z + c3.w*t3.w;
                }
                part = (a0 + a1) + (a2 + a3);
            }
            // full dot within the 4-lane group (ci uniform across the group)
            float d = part;
            d += __shfl_xor(d, 1);
            d += __shfl_xor(d, 2);
            if (ci >= nc) d = -3.4e38f;
            // cross-group argmax, lowest-index tie-break
            #pragma unroll
            for (int msk = 4; msk < 64; msk <<= 1) {
                float od = __shfl_xor(d, msk);
                int   oc = __shfl_xor(code, msk);
                if (od > d || (od == d && oc < code)) { d = od; code = oc; }
            }
            if (d > bv || (d == bv && code < bi)) { bv = d; bi = code; }
        }
        if (lane == 0) out[n0 + tok] = bi;
    }
}

extern "C" void kernel_launch(void* const* d_in, const int* in_sizes, int n_in,
                              void* d_out, int out_size, void* d_ws, size_t ws_size,
                              hipStream_t stream) {
    const float* fbank = (const float*)d_in[0];   // 16 x 8192 x 128
    const float* convw = (const float*)d_in[1];   // [512][256]
    const float* proj  = (const float*)d_in[2];   // [512][256]
    const float* cbook = (const float*)d_in[3];   // [1024][256]
    int* out = (int*)d_out;                       // 65536 int32

    char* ws = (char*)d_ws;
    ushort_t* cbph = (ushort_t*)ws;                  // 512 KB codebook h-plane
    float* cbn     = (float*)(ws + 0x080000);        // 1 MB normalized codebook fp32
    ushort_t* w2p  = (ushort_t*)(ws + 0x180000);     // 384 KB M planes (split-3)
    float* wsum    = (float*)(ws + 0x1E0000);        // 1 KB
    float* p1      = (float*)(ws + 0x1E1000);        // 1 KB

    hipLaunchKernelGGL(k_pre,  dim3(257),  dim3(512), 0, stream,
                       convw, proj, cbook, cbph, cbn, w2p, wsum, p1);
    hipLaunchKernelGGL(k_mega, dim3(2048), dim3(512), 0, stream,
                       fbank, w2p, cbph, cbn, wsum, p1, out);
}

// Round 9
// 277.547 us; speedup vs baseline: 1.2301x; 1.0767x over previous
//
#include <hip/hip_runtime.h>
#include <math.h>

#define QD 256
#define QN 1024
#define TT 8192

typedef __bf16 bf16x8 __attribute__((ext_vector_type(8)));
typedef float  f32x16 __attribute__((ext_vector_type(16)));
typedef unsigned short ushort_t;
typedef unsigned short us8 __attribute__((ext_vector_type(8)));
typedef unsigned short us4 __attribute__((ext_vector_type(4)));

// LDS map (k_mega), total 54784 -> 2 blocks/CU
#define PL  0        // A planes [3][16kc][64cl][16B] = 49152 ; after GEMM1: t-h [0,16K), t32 [16K,48K)
#define MU_ 49152    // muS[8][32] f32 = 1024 (wave-pre-reduced)
#define LM_ 50176    // lnMu[32] f32
#define T2_ 50304    // tn2A[32] f32 (atomicAdd)
#define TR_ 50432    // thrR[32] u32 (atomicMax, order-encoded)
#define CN_ 50560    // cnt[32] i32
#define CC_ 50688    // candC[32][48] u16 = 3072
#define P1_ 53760    // p1S[256] f32 = 1024
#define SMEM_TOTAL 54784
#define CCAP 48

// exact 3-way bf16 split (truncation; x = h+m+l up to ~2^-21|x|)
__device__ __forceinline__ void split3(float x, ushort_t& h, ushort_t& m, ushort_t& l) {
    unsigned int xu = __float_as_uint(x);
    h = (ushort_t)(xu >> 16);
    float hf = __uint_as_float(xu & 0xFFFF0000u);
    float r1 = x - hf;                       // exact
    unsigned int r1u = __float_as_uint(r1);
    m = (ushort_t)(r1u >> 16);
    float mf = __uint_as_float(r1u & 0xFFFF0000u);
    float r2 = r1 - mf;                      // exact
    l = (ushort_t)(__float_as_uint(r2) >> 16);
}
__device__ __forceinline__ f32x16 MF(bf16x8 a, bf16x8 b, f32x16 c) {
    return __builtin_amdgcn_mfma_f32_32x32x16_bf16(a, b, c, 0, 0, 0);
}
// order-preserving float<->uint encode (for atomicMax on float values); init 0 < all encodings
__device__ __forceinline__ unsigned fenc(float f) {
    unsigned u = __float_as_uint(f);
    return (u & 0x80000000u) ? ~u : (u | 0x80000000u);
}
__device__ __forceinline__ float fdec(unsigned u) {
    return (u & 0x80000000u) ? __uint_as_float(u ^ 0x80000000u) : __uint_as_float(~u);
}

// ---------- k_pre v2 (r8 verbatim): parallel + coalesced; numerics bit-identical ----------
__global__ __launch_bounds__(512) void k_pre(const float* __restrict__ convw,
                                             const float* __restrict__ proj,
                                             const float* __restrict__ cb,
                                             ushort_t* __restrict__ cbph,
                                             float* __restrict__ cbn,
                                             ushort_t* __restrict__ w2p,
                                             float* __restrict__ wsum,
                                             float* __restrict__ p1) {
    int bx = blockIdx.x, t = threadIdx.x;
    if (bx < 128) {
        int w = t >> 6, lane = t & 63;
        int c = bx*8 + w;
        float4 v = ((const float4*)(cb + (size_t)c*QD))[lane];
        float ss = v.x*v.x + v.y*v.y + v.z*v.z + v.w*v.w;
        #pragma unroll
        for (int off = 32; off > 0; off >>= 1) ss += __shfl_down(ss, off);
        ss = __shfl(ss, 0);
        float inv = 1.0f/fmaxf(sqrtf(ss), 1e-12f);
        float4 vn = make_float4(v.x*inv, v.y*inv, v.z*inv, v.w*inv);
        *(float4*)(cbn + (size_t)c*QD + 4*lane) = vn;
        int k0 = 4*lane;
        size_t base = ((size_t)(k0>>4)*32 + (c>>5))*512 + (((k0>>3)&1)*32 + (c&31))*8 + (k0&7);
        us4 hv4;
        hv4[0] = (ushort_t)(__float_as_uint(vn.x) >> 16);
        hv4[1] = (ushort_t)(__float_as_uint(vn.y) >> 16);
        hv4[2] = (ushort_t)(__float_as_uint(vn.z) >> 16);
        hv4[3] = (ushort_t)(__float_as_uint(vn.w) >> 16);
        *(us4*)(cbph + base) = hv4;
    } else if (bx < 256) {
        int col0 = (bx - 128)*2;
        int tt = t & 255, cs = t >> 8;
        int col = col0 + cs;
        __shared__ float colv[2][512];
        colv[cs][tt]       = proj[(size_t)tt*256 + col];
        colv[cs][tt + 256] = proj[(size_t)(tt+256)*256 + col];
        __syncthreads();
        float acc = 0.f;
        #pragma unroll 32
        for (int d = 0; d < 512; ++d) acc += convw[d*256 + tt] * colv[cs][d];
        ushort_t hb, mb, lb; split3(acc, hb, mb, lb);
        size_t base = ((size_t)(tt>>4)*8 + (col>>5))*512 + (((tt>>3)&1)*32 + (col&31))*8 + (tt&7);
        w2p[base] = hb;
        w2p[base + 65536] = mb;
        w2p[base + 131072] = lb;
    } else {
        if (t < 256) {
            float s = 0.f;
            #pragma unroll 32
            for (int d = 0; d < 512; ++d) s += convw[d*256 + t];
            wsum[t] = s;
        } else {
            int u = t - 256;
            float s = 0.f;
            #pragma unroll 32
            for (int d = 0; d < 512; ++d) s += proj[d*256 + u];
            p1[u] = s;
        }
    }
}

// ---------- k_mega: r8 structure with BOTH GEMMs operand-swapped (C transposed) so the
//            reduction axis (q for ||t||^2, codes for max) is lane-local: shuffle trees
//            (240 DPP ops/thread) collapse to 2 shfl + 2 LDS atomics. sim/t values identical. ----
__global__ __launch_bounds__(512, 4) void k_mega(const float* __restrict__ fbank,
                                                 const ushort_t* __restrict__ w2p,
                                                 const ushort_t* __restrict__ cbph,
                                                 const float* __restrict__ cbn,
                                                 const float* __restrict__ wsum,
                                                 const float* __restrict__ p1,
                                                 int* __restrict__ out) {
    __shared__ char smem[SMEM_TOTAL];
    float*    muS   = (float*)(smem + MU_);
    float*    lnMuS = (float*)(smem + LM_);
    float*    tn2A  = (float*)(smem + T2_);
    unsigned* thrR  = (unsigned*)(smem + TR_);
    int*      cntS  = (int*)(smem + CN_);
    ushort_t* candS = (ushort_t*)(smem + CC_);
    float*    p1S   = (float*)(smem + P1_);

    int tid = threadIdx.x;
    int n0 = blockIdx.x * 32;
    int w = tid >> 6, lane = tid & 63;
    int n31 = lane & 31, h = lane >> 5;
    size_t loff = (size_t)lane * 16;
    const char* w2pc = (const char*)w2p;
    const char* cbhc = (const char*)cbph;

    auto loadB1 = [&](int kcv, bf16x8 (&dst)[3]) {
        #pragma unroll
        for (int q = 0; q < 3; ++q)
            dst[q] = *(const bf16x8*)(w2pc + (size_t)q*131072 + (size_t)(kcv*8 + w)*1024 + loff);
    };
    // sweep sw covers code tiles 16sw + {w, w+8}
    auto loadB2s = [&](int sw, int kcv, bf16x8 (&dst)[2]) {
        dst[0] = *(const bf16x8*)(cbhc + (size_t)(kcv*32 + 16*sw + w    )*1024 + loff);
        dst[1] = *(const bf16x8*)(cbhc + (size_t)(kcv*32 + 16*sw + w + 8)*1024 + loff);
    };
    auto loadA = [&](int kcv, bf16x8 (&a)[3]) {
        #pragma unroll
        for (int p = 0; p < 3; ++p)
            a[p] = *(const bf16x8*)(smem + p*16384 + kcv*1024 + loff);
    };
    // x = w2p planes (A operand), y = patch planes (B operand); pairs (p,q), p+q<=2
    auto compute6 = [&](bf16x8 (&x)[3], bf16x8 (&y)[3], f32x16& acc) {
        acc = MF(x[0], y[0], acc);
        acc = MF(x[0], y[1], acc);
        acc = MF(x[1], y[0], acc);
        acc = MF(x[1], y[1], acc);
        acc = MF(x[0], y[2], acc);
        acc = MF(x[2], y[0], acc);
    };

    // ---- prefetch fbank (4 float4/thread) + wsum slices (L2-hot after first blocks) ----
    float4 va[2], vb[2];
    #pragma unroll
    for (int i = 0; i < 2; ++i) {
        int id = tid + 512*i;
        int kc = id >> 6, cl = id & 63;
        int tok = cl & 31, hh2 = cl >> 5;
        int n = n0 + tok;
        int b = n >> 12, r = n & 4095, th = r >> 3, wm = r & 7;
        const float* src = fbank + ((size_t)(b*TT + th*16 + kc))*128 + wm*16 + hh2*8;
        va[i] = ((const float4*)src)[0];
        vb[i] = ((const float4*)src)[1];
    }
    int wb0 = 16*(tid >> 6) + 8*((tid >> 5) & 1);
    float4 w00 = *(const float4*)(wsum + wb0);
    float4 w01 = *(const float4*)(wsum + wb0 + 4);
    float4 w10 = *(const float4*)(wsum + wb0 + 128);
    float4 w11 = *(const float4*)(wsum + wb0 + 132);

    if (tid < 32) { tn2A[tid] = 0.f; thrR[tid] = 0u; cntS[tid] = 0; }
    if (tid < 256) p1S[tid] = p1[tid];

    float wsv[2][8];
    wsv[0][0]=w00.x; wsv[0][1]=w00.y; wsv[0][2]=w00.z; wsv[0][3]=w00.w;
    wsv[0][4]=w01.x; wsv[0][5]=w01.y; wsv[0][6]=w01.z; wsv[0][7]=w01.w;
    wsv[1][0]=w10.x; wsv[1][1]=w10.y; wsv[1][2]=w10.z; wsv[1][3]=w10.w;
    wsv[1][4]=w11.x; wsv[1][5]=w11.y; wsv[1][6]=w11.z; wsv[1][7]=w11.w;

    // ---- stage patch -> 3 bf16 planes; mu partial (exact fp32 vals) folded in ----
    float mupart = 0.f;
    #pragma unroll
    for (int i = 0; i < 2; ++i) {
        int id = tid + 512*i;
        int kc = id >> 6, cl = id & 63;
        float vals[8] = {va[i].x, va[i].y, va[i].z, va[i].w, vb[i].x, vb[i].y, vb[i].z, vb[i].w};
        us8 hv, mv, lv;
        #pragma unroll
        for (int j = 0; j < 8; ++j) {
            ushort_t a_, b_, c_; split3(vals[j], a_, b_, c_);
            hv[j] = a_; mv[j] = b_; lv[j] = c_;
            mupart += vals[j] * wsv[i][j];
        }
        char* cp = smem + kc*1024 + cl*16;
        *(us8*)cp = hv;
        *(us8*)(cp + 16384) = mv;
        *(us8*)(cp + 32768) = lv;
    }

    // first GEMM1 A-tile (w2p): in flight under muS store + barrier drain
    bf16x8 bA[3], bB[3];
    loadB1(0, bA);

    // wave pre-reduce mu partials (token = tid&31 appears in lanes l and l+32)
    float mu2 = mupart + __shfl_xor(mupart, 32);
    if (lane < 32) muS[w*32 + lane] = mu2;
    __syncthreads();                                   // B2: planes + muS + p1S + inits ready

    if (tid < 32) {
        float pm = 0.f;
        #pragma unroll
        for (int s = 0; s < 8; ++s) pm += muS[s*32 + tid];
        lnMuS[tid] = pm * (1.f/512.f);                 // published at B3
    }

    // ========== GEMM1 (swapped): C[q_local][token] = M_tile^T-ish @ patch, 6 products ======
    f32x16 accE, accO;
    #pragma unroll
    for (int r2 = 0; r2 < 16; ++r2) { accE[r2] = 0.f; accO[r2] = 0.f; }
    for (int kc = 0; kc < 16; kc += 2) {
        loadB1(kc + 1, bB);
        { bf16x8 a[3]; loadA(kc, a); compute6(bA, a, accE); }
        if (kc + 2 < 16) loadB1(kc + 2, bA);
        { bf16x8 a[3]; loadA(kc + 1, a); compute6(bB, a, accO); }
    }

    bf16x8 qA[2], qB[2];
    loadB2s(0, 0, qA);                                 // flies across epilogue (drains at B3)

    __syncthreads();                                   // B3: GEMM1 LDS reads done; lnMu ready

    // ---- t = V - mu*p1: lane owns token t31=n31, 16 q's. ||t||^2 lane-local (no tree).
    //      t-h -> [0,16K) exact operand packing; t32 -> [16K,48K) chunk-XOR swizzled. ----
    {
        int t31 = n31;
        float muv = lnMuS[t31];
        int s = t31 & 7;
        float sqacc = 0.f;
        #pragma unroll
        for (int reg = 0; reg < 16; ++reg) {
            int ql = (reg&3) + 8*(reg>>2) + 4*h;
            int q = 32*w + ql;
            float tv = (accE[reg] + accO[reg]) - muv * p1S[q];
            *(float*)(smem + 16384 + t31*1024 + (((q>>2)^s)<<4) + (q&3)*4) = tv;
            *(ushort_t*)(smem + (q>>4)*1024 + (((q>>3)&1)*32 + t31)*16 + (q&7)*2)
                = (ushort_t)(__float_as_uint(tv) >> 16);
            sqacc += tv*tv;
        }
        sqacc += __shfl_xor(sqacc, 32);                // combine h-halves (32 q's of this wave)
        if (h == 0) atomicAdd(&tn2A[t31], sqacc);      // 8 waves x 32 q = 256
    }
    __syncthreads();                                   // B4: t-h / t32 / tn2A ready

    // ========== GEMM2 screen (swapped): C[code_local][token]; lane holds 32 codes of 1 token ==
    #pragma unroll
    for (int sw = 0; sw < 2; ++sw) {
        f32x16 s0, s1;
        #pragma unroll
        for (int r2 = 0; r2 < 16; ++r2) { s0[r2] = 0.f; s1[r2] = 0.f; }
        for (int kc = 0; kc < 16; kc += 2) {
            loadB2s(sw, kc + 1, qB);
            {
                bf16x8 th = *(const bf16x8*)(smem + kc*1024 + loff);
                s0 = MF(qA[0], th, s0); s1 = MF(qA[1], th, s1);
            }
            if (kc + 2 < 16) loadB2s(sw, kc + 2, qA);
            else if (sw == 0) loadB2s(1, 0, qA);       // preload next sweep across barrier
            {
                bf16x8 th = *(const bf16x8*)(smem + (kc+1)*1024 + loff);
                s0 = MF(qB[0], th, s0); s1 = MF(qB[1], th, s1);
            }
        }
        // lane-local max over 32 codes -> h-combine -> atomicMax (2 DS ops total)
        {
            float m = fmaxf(s0[0], s1[0]);
            #pragma unroll
            for (int r2 = 1; r2 < 16; ++r2) m = fmaxf(m, fmaxf(s0[r2], s1[r2]));
            m = fmaxf(m, __shfl_xor(m, 32));
            if (h == 0) atomicMax(&thrR[n31], fenc(m));
        }
        __syncthreads();                               // B5/B6: this sweep's maxes visible
        // append candidates; thr read once per thread. Later-sweep contamination only RAISES
        // thr and stays >= globalmax - window; window 0.04 > 2e = 0.032 keeps argmax in set.
        {
            float th_ = fdec(thrR[n31]) - 0.04f*sqrtf(tn2A[n31]);
            int cb0 = 32*(16*sw + w), cb1 = 32*(16*sw + w + 8);
            #pragma unroll
            for (int reg = 0; reg < 16; ++reg) {
                int cloc = (reg&3) + 8*(reg>>2) + 4*h;
                if (s0[reg] >= th_) { int p = atomicAdd(&cntS[n31], 1); if (p < CCAP) candS[n31*CCAP + p] = (ushort_t)(cb0 + cloc); }
                if (s1[reg] >= th_) { int p = atomicAdd(&cntS[n31], 1); if (p < CCAP) candS[n31*CCAP + p] = (ushort_t)(cb1 + cloc); }
            }
        }
    }
    __syncthreads();                                   // B7: candidates final

    // ---- exact fp32 refine: 16 candidates in parallel (4-lane groups); wave w owns 4 tokens.
    //      t32 is chunk-XOR swizzled: storage chunk cs holds true chunk cs^s (s=tok&7); pair
    //      tpS[cs] with cbn chunk cs^s — pure reordering of the exact sum. ----
    int grp = lane >> 2, sub = lane & 3;
    #pragma unroll 1
    for (int tk = 0; tk < 4; ++tk) {
        int tok = 4*w + tk;
        int s = tok & 7;
        int cnt = cntS[tok];
        bool full = (cnt > CCAP);                      // provable fallback: scan everything
        int nc = full ? 1024 : cnt;
        const float4* tp4 = (const float4*)(smem + 16384 + (size_t)tok*1024);
        float bv = -3.4e38f; int bi = 0x7fffffff;
        #pragma unroll 1
        for (int base = 0; base < nc; base += 16) {
            int ci = base + grp;
            int code = 0x7fffffff;
            float part = 0.f;
            if (ci < nc) {
                code = full ? ci : (int)candS[tok*CCAP + ci];
                const float4* cp4 = (const float4*)(cbn + (size_t)code*256);
                float a0 = 0.f, a1 = 0.f, a2 = 0.f, a3 = 0.f;
                #pragma unroll
                for (int jj = 0; jj < 16; jj += 4) {
                    int i0 = (jj  )*4 + sub, i1 = (jj+1)*4 + sub;
                    int i2 = (jj+2)*4 + sub, i3 = (jj+3)*4 + sub;
                    float4 t0 = tp4[i0], c0 = cp4[i0 ^ s];
                    float4 t1 = tp4[i1], c1 = cp4[i1 ^ s];
                    float4 t2 = tp4[i2], c2 = cp4[i2 ^ s];
                    float4 t3 = tp4[i3], c3 = cp4[i3 ^ s];
                    a0 += c0.x*t0.x + c0.y*t0.y + c0.z*t0.z + c0.w*t0.w;
                    a1 += c1.x*t1.x + c1.y*t1.y + c1.z*t1.z + c1.w*t1.w;
                    a2 += c2.x*t2.x + c2.y*t2.y + c2.z*t2.z + c2.w*t2.w;
                    a3 += c3.x*t3.x + c3.y*t3.y + c3.z*t3.z + c3.w*t3.w;
                }
                part = (a0 + a1) + (a2 + a3);
            }
            // full dot within the 4-lane group (ci uniform across the group)
            float d = part;
            d += __shfl_xor(d, 1);
            d += __shfl_xor(d, 2);
            if (ci >= nc) d = -3.4e38f;
            // cross-group argmax, lowest-index tie-break
            #pragma unroll
            for (int msk = 4; msk < 64; msk <<= 1) {
                float od = __shfl_xor(d, msk);
                int   oc = __shfl_xor(code, msk);
                if (od > d || (od == d && oc < code)) { d = od; code = oc; }
            }
            if (d > bv || (d == bv && code < bi)) { bv = d; bi = code; }
        }
        if (lane == 0) out[n0 + tok] = bi;
    }
}

extern "C" void kernel_launch(void* const* d_in, const int* in_sizes, int n_in,
                              void* d_out, int out_size, void* d_ws, size_t ws_size,
                              hipStream_t stream) {
    const float* fbank = (const float*)d_in[0];   // 16 x 8192 x 128
    const float* convw = (const float*)d_in[1];   // [512][256]
    const float* proj  = (const float*)d_in[2];   // [512][256]
    const float* cbook = (const float*)d_in[3];   // [1024][256]
    int* out = (int*)d_out;                       // 65536 int32

    char* ws = (char*)d_ws;
    ushort_t* cbph = (ushort_t*)ws;                  // 512 KB codebook h-plane
    float* cbn     = (float*)(ws + 0x080000);        // 1 MB normalized codebook fp32
    ushort_t* w2p  = (ushort_t*)(ws + 0x180000);     // 384 KB M planes (split-3)
    float* wsum    = (float*)(ws + 0x1E0000);        // 1 KB
    float* p1      = (float*)(ws + 0x1E1000);        // 1 KB

    hipLaunchKernelGGL(k_pre,  dim3(257),  dim3(512), 0, stream,
                       convw, proj, cbook, cbph, cbn, w2p, wsum, p1);
    hipLaunchKernelGGL(k_mega, dim3(2048), dim3(512), 0, stream,
                       fbank, w2p, cbph, cbn, wsum, p1, out);
}